// Round 5
// baseline (415.630 us; speedup 1.0000x reference)
//
#include <hip/hip_runtime.h>

// ConvMlp4d: conv4d(64->128) + bias + relu -> conv4d(128->64) + bias.
// R5: flat unit-stream K-loop with cross-unit DMA pipelining. Stage in
// 32-channel units (ping-pong buffers, 2x24576 B LDS); ONE barrier per unit;
// unit i+1's global_load_lds issued right after the barrier so the next
// barrier's vmcnt(0) drain has a full unit of MFMA lead time. Inner loop per
// (ks,kw): 6 ds_read_b128 + 6 (NT=2) B-loads batched before 24 MFMAs.
//   ws: x_t bf16 [2][65536][64] | h_t bf16 [2][65536][128]
//       w1t bf16 [81][4][128][16] | w2t bf16 [81][8][64][16] | zeropad 256B

using bf16x8 = __attribute__((ext_vector_type(8))) __bf16;
using f32x16 = __attribute__((ext_vector_type(16))) float;
using f32x4  = __attribute__((ext_vector_type(4))) float;

typedef __attribute__((address_space(1))) const void as1_void;
typedef __attribute__((address_space(3))) void as3_void;
__device__ __forceinline__ void gload_lds16(const void* g, void* l) {
    __builtin_amdgcn_global_load_lds((as1_void*)g, (as3_void*)l, 16, 0, 0);
}

// ---------------- prep: x (2,64,65536) f32 -> x_t (2,65536,64) bf16 ----------------
__global__ __launch_bounds__(256) void cvt_x(const float* __restrict__ x,
                                             __bf16* __restrict__ x_t) {
    __shared__ float lt[64][65];
    const int nb = blockIdx.y;
    const int p0 = blockIdx.x * 64;
    const float* src = x + (size_t)nb * 64 * 65536;
    __bf16* dst = x_t + (size_t)nb * 65536 * 64;
    #pragma unroll
    for (int i = 0; i < 16; ++i) {
        int idx = i * 256 + threadIdx.x;
        int c = idx >> 6, p = idx & 63;
        lt[c][p] = src[(size_t)c * 65536 + p0 + p];
    }
    __syncthreads();
    #pragma unroll
    for (int i = 0; i < 16; ++i) {
        int idx = i * 256 + threadIdx.x;
        int p = idx >> 6, c = idx & 63;
        dst[(size_t)(p0 + p) * 64 + c] = (__bf16)lt[c][p];
    }
}

// ------- prep: w (O,CIN,81) f32 -> wt [81][CIN/16][COUT][16] bf16 (frag-coalesced) --
template <int CIN>
__global__ __launch_bounds__(256) void cvt_w(const float* __restrict__ w,
                                             __bf16* __restrict__ wt) {
    constexpr int LOG = (CIN == 64) ? 6 : 7;
    constexpr int COUT = 8192 / CIN;
    int oc = blockIdx.x * 256 + threadIdx.x;          // o*CIN + c
    if (oc >= 8192) return;
    const int o = oc >> LOG, c = oc & (CIN - 1);
    const int kg = c >> 4, cl = c & 15;
    const float* src = w + (size_t)oc * 81;
    #pragma unroll 1
    for (int tap = 0; tap < 81; ++tap)
        wt[(((size_t)tap * (CIN / 16) + kg) * COUT + o) * 16 + cl] = (__bf16)src[tap];
}

// ---------------- fused conv4d (implicit GEMM, 32x32x16 bf16 MFMA) -----------------
// Block 256 thr = 4 waves (2m x 2n). Block tile M=256 (v-span 8), N=2*NT*32.
// Staging unit = one (kt,ku) stage x 32 channels: [row10][chunk4][wp34] x 16B
// = 21760 B in a 24576 B ping-pong buffer (slot overflow padding). Flat unit
// stream: barrier; issue DMA(unit i+1); compute(unit i).
template <int CIN, int COUT, int NT, bool RELU>
__global__ __launch_bounds__(256, 2) void conv4d_mfma(
    const __bf16* __restrict__ in_t,   // [2][65536][CIN] channels-last
    const __bf16* __restrict__ wt,     // [81][CIN/16][COUT][16]
    const float* __restrict__ bias,    // [COUT]
    __bf16* __restrict__ out_bf,       // [2][65536][COUT]  (RELU path)
    float* __restrict__ out_f,         // [2][COUT][65536]  (else)
    const __bf16* __restrict__ zp)     // 256B zero page
{
    constexpr int KST   = CIN / 16;    // 16-ch groups total
    constexpr int UNITS = CIN / 32;    // staging units per stage
    constexpr int LOGU  = (UNITS == 2) ? 1 : 2;
    __shared__ __bf16 tile[2 * 12288]; // 2 x 24576 B ping-pong

    const int tid  = threadIdx.x;
    const int lane = tid & 63;
    const int l31  = lane & 31;
    const int hl   = lane >> 5;
    const int wv   = tid >> 6;
    const int gmi  = wv >> 1;          // m wave-row 0..1
    const int gni  = wv & 1;           // n wave-col 0..1

    // grid swizzle: xcd(3b) | ulo(1b) | vg(2b) | t(2b) | nb(1b); u = xcd*2+ulo
    const int bid = blockIdx.x;
    const int xcd = bid & 7;
    const int s0  = bid >> 3;
    const int u   = xcd * 2 + (s0 & 1);
    const int vg  = (s0 >> 1) & 3;
    const int t   = (s0 >> 3) & 3;
    const int nb  = (s0 >> 5) & 1;
    const int v0  = vg * 8;
    const int pbase = ((t * 16 + u) * 32 + v0) * 32;

    const __bf16* inb = in_t + (size_t)nb * 65536 * CIN;

    // ---- per-lane staging offsets for the 6 DMA rounds (slot = r*256 + tid) ----
    int goff[6];
    #pragma unroll
    for (int r = 0; r < 6; ++r) {
        const int slot = r * 256 + tid;            // 16B-chunk slot
        const int row  = slot / 136;               // [row][chunk4][wp34]
        const int rem  = slot - row * 136;
        const int chunk = rem / 34;
        const int wp   = rem - chunk * 34;
        const int v_in = v0 - 1 + row;
        const int w_in = wp - 1;
        const bool ok = (row < 10) && ((unsigned)v_in < 32u) && ((unsigned)w_in < 32u);
        goff[r] = ok ? ((v_in * 32 + w_in) * CIN + chunk * 8) : -1;
    }

    // A-read lane base (16B units): idx = (gmi*16 + r*4 + ks*2 + hl)*34 + l31 + kw
    const int lane_base = (gmi * 16 + hl) * 34 + l31;
    const bf16x8* tile16 = (const bf16x8*)tile;

    // B lane pointers (elements): o = (gni*NT+nt)*32 + l31; + hl*8 within 16ch
    const __bf16* wlane[NT];
    #pragma unroll
    for (int nt = 0; nt < NT; ++nt)
        wlane[nt] = wt + ((gni * NT + nt) * 32 + l31) * 16 + hl * 8;

    // ---- valid stage list (block-uniform, SGPRs) ----
    int sb[9], tb0[9], nst = 0;
    #pragma unroll
    for (int kt = 0; kt < 3; ++kt) {
        const int t_in = t + kt - 1;
        if ((unsigned)t_in >= 4u) continue;
        #pragma unroll
        for (int ku = 0; ku < 3; ++ku) {
            const int u_in = u + ku - 1;
            if ((unsigned)u_in >= 16u) continue;
            sb[nst]  = (t_in * 16 + u_in) * 1024 * CIN;   // element offset
            tb0[nst] = (kt * 3 + ku) * 9;
            ++nst;
        }
    }
    const int U = nst * UNITS;

    f32x16 acc[4][NT];
    #pragma unroll
    for (int mt = 0; mt < 4; ++mt)
        #pragma unroll
        for (int nt = 0; nt < NT; ++nt)
            #pragma unroll
            for (int i = 0; i < 16; ++i)
                acc[mt][nt][i] = 0.f;

    // DMA issue for unit j: 6 rounds x (wave-uniform base + lane*16)
    auto issue = [&](int j) {
        const int st = j >> LOGU, ch = j & (UNITS - 1);
        const __bf16* gb = inb + sb[st] + ch * 32;
        char* lb = ((char*)tile) + (j & 1) * 24576 + wv * 1024;
        #pragma unroll
        for (int r = 0; r < 6; ++r) {
            const __bf16* gp = (goff[r] >= 0) ? (gb + goff[r]) : zp;
            gload_lds16(gp, lb + r * 4096);
        }
    };

    issue(0);
    #pragma unroll 1
    for (int i = 0; i < U; ++i) {
        __syncthreads();               // vmcnt(0) drain: unit-i DMA had a full
                                       // unit of compute lead time (except i=0)
        if (i + 1 < U) issue(i + 1);

        const int st = i >> LOGU, ch = i & (UNITS - 1);
        const int tapb = tb0[st];
        const bf16x8* tb = tile16 + (i & 1) * 1536 + lane_base;
        #pragma unroll
        for (int ks = 0; ks < 2; ++ks) {
            const int ksg = ch * 2 + ks;
            #pragma unroll
            for (int kw = 0; kw < 3; ++kw) {
                bf16x8 af[6];
                #pragma unroll
                for (int r = 0; r < 6; ++r)
                    af[r] = tb[kw + 34 * (4 * r + 2 * ks)];
                bf16x8 bv[3][NT];
                #pragma unroll
                for (int kv = 0; kv < 3; ++kv) {
                    const size_t wo =
                        ((size_t)(tapb + kv * 3 + kw) * KST + ksg) * (COUT * 16);
                    #pragma unroll
                    for (int nt = 0; nt < NT; ++nt)
                        bv[kv][nt] = *(const bf16x8*)(wlane[nt] + wo);
                }
                #pragma unroll
                for (int kv = 0; kv < 3; ++kv)
                    #pragma unroll
                    for (int rr = 0; rr < 4; ++rr)
                        #pragma unroll
                        for (int nt = 0; nt < NT; ++nt)
                            acc[rr][nt] = __builtin_amdgcn_mfma_f32_32x32x16_bf16(
                                af[kv + rr], bv[kv][nt], acc[rr][nt], 0, 0, 0);
            }
        }
    }

    // ---- epilogue: C/D 32x32: col = lane&31, row = (reg&3) + 8*(reg>>2) + 4*hl ----
    #pragma unroll
    for (int nt = 0; nt < NT; ++nt) {
        const int o = (gni * NT + nt) * 32 + l31;
        const float bvls = bias[o];
        #pragma unroll
        for (int mt = 0; mt < 4; ++mt) {
            const int pb = pbase + (gmi * 4 + mt) * 32;
            if constexpr (RELU) {
                #pragma unroll
                for (int rg = 0; rg < 4; ++rg)
                    #pragma unroll
                    for (int j = 0; j < 4; ++j) {
                        float v = acc[mt][nt][rg * 4 + j] + bvls;
                        v = v > 0.f ? v : 0.f;
                        const int p = pb + j + 8 * rg + 4 * hl;
                        out_bf[(size_t)(nb * 65536 + p) * COUT + o] = (__bf16)v;
                    }
            } else {
                #pragma unroll
                for (int rg = 0; rg < 4; ++rg) {
                    f32x4 sv;
                    #pragma unroll
                    for (int j = 0; j < 4; ++j)
                        sv[j] = acc[mt][nt][rg * 4 + j] + bvls;
                    const int p = pb + 8 * rg + 4 * hl;
                    *(f32x4*)(out_f + ((size_t)nb * COUT + o) * 65536 + p) = sv;
                }
            }
        }
    }
}

extern "C" void kernel_launch(void* const* d_in, const int* in_sizes, int n_in,
                              void* d_out, int out_size, void* d_ws, size_t ws_size,
                              hipStream_t stream) {
    const float* x  = (const float*)d_in[0];
    const float* w1 = (const float*)d_in[1];
    const float* b1 = (const float*)d_in[2];
    const float* w2 = (const float*)d_in[3];
    const float* b2 = (const float*)d_in[4];
    float* out = (float*)d_out;

    char* ws = (char*)d_ws;
    __bf16* x_t = (__bf16*)ws;                               // 16,777,216 B
    __bf16* h_t = (__bf16*)(ws + 16777216);                  // 33,554,432 B
    __bf16* w1t = (__bf16*)(ws + 50331648);                  //  1,327,104 B
    __bf16* w2t = (__bf16*)(ws + 51658752);                  //  1,327,104 B
    __bf16* zp  = (__bf16*)(ws + 52985856);                  //        256 B

    hipMemsetAsync(zp, 0, 256, stream);
    cvt_x<<<dim3(1024, 2), 256, 0, stream>>>(x, x_t);
    cvt_w<64><<<32, 256, 0, stream>>>(w1, w1t);
    cvt_w<128><<<32, 256, 0, stream>>>(w2, w2t);

    // conv1: wave 128x64 (NT=2), 2 units/stage, relu -> bf16 channels-last
    conv4d_mfma<64, 128, 2, true><<<512, 256, 0, stream>>>(x_t, w1t, b1, h_t,
                                                           nullptr, zp);
    // conv2: wave 128x32 (NT=1), 4 units/stage, fp32 planar out
    conv4d_mfma<128, 64, 1, false><<<512, 256, 0, stream>>>(h_t, w2t, b2, nullptr,
                                                            out, zp);
}

// Round 7
// 397.754 us; speedup vs baseline: 1.0449x; 1.0449x over previous
//
#include <hip/hip_runtime.h>

// ConvMlp4d: conv4d(64->128) + bias + relu -> conv4d(128->64) + bias.
// R7: (a) race fix — explicit s_waitcnt vmcnt(0) before every barrier (LDS-DMA
// has no VGPR dest; compiler waitcnt insertion can miss it -> R6's replay-time
// divergence), exec-masked DMA + one-time LDS zero pre-fill of halo slots
// (zero page + memset removed). (b) parallelism — v-span 4 blocks (M=128,
// unit 13056 B, ping-pong 26112 B LDS), 1024 blocks/conv, 3-4 blocks/CU
// (R4-R6 were stuck at 2 blocks/CU, latency-bound at ~2.5 GB/s/CU).
//   ws: x_t bf16 [2][65536][64] | h_t bf16 [2][65536][128] (both chunk-planar:
//       [nb][tu][v][chunk=c/8][w][c%8])
//       w1t bf16 [81][4][128][16] | w2t bf16 [81][8][64][16]

using bf16x8 = __attribute__((ext_vector_type(8))) __bf16;
using f32x16 = __attribute__((ext_vector_type(16))) float;
using f32x4  = __attribute__((ext_vector_type(4))) float;

typedef __attribute__((address_space(1))) const void as1_void;
typedef __attribute__((address_space(3))) void as3_void;
__device__ __forceinline__ void gload_lds16(const void* g, void* l) {
    __builtin_amdgcn_global_load_lds((as1_void*)g, (as3_void*)l, 16, 0, 0);
}

// ------- prep: x (2,64,65536) f32 -> x_t chunk-planar bf16 -------------------------
__global__ __launch_bounds__(256) void cvt_x(const float* __restrict__ x,
                                             __bf16* __restrict__ x_t) {
    __shared__ float lt[64][65];
    const int nb = blockIdx.y;
    const int p0 = blockIdx.x * 64;
    const int tu = p0 >> 10;
    const float* src = x + (size_t)nb * 64 * 65536;
    __bf16* dst = x_t + (size_t)nb * 65536 * 64;
    #pragma unroll
    for (int i = 0; i < 16; ++i) {
        int idx = i * 256 + threadIdx.x;
        int c = idx >> 6, p = idx & 63;
        lt[c][p] = src[(size_t)c * 65536 + p0 + p];
    }
    __syncthreads();
    #pragma unroll
    for (int i = 0; i < 16; ++i) {
        int idx = i * 256 + threadIdx.x;
        int c = idx >> 6, pl = idx & 63;
        int p = p0 + pl;
        int v = (p >> 5) & 31, w = p & 31;
        dst[(size_t)(tu * 32 + v) * 2048 + (c >> 3) * 256 + w * 8 + (c & 7)] =
            (__bf16)lt[c][pl];
    }
}

// ------- prep: w (O,CIN,81) f32 -> wt [81][CIN/16][COUT][16] bf16 ------------------
template <int CIN>
__global__ __launch_bounds__(256) void cvt_w(const float* __restrict__ w,
                                             __bf16* __restrict__ wt) {
    constexpr int LOG = (CIN == 64) ? 6 : 7;
    constexpr int COUT = 8192 / CIN;
    int oc = blockIdx.x * 256 + threadIdx.x;
    if (oc >= 8192) return;
    const int o = oc >> LOG, c = oc & (CIN - 1);
    const int kg = c >> 4, cl = c & 15;
    const float* src = w + (size_t)oc * 81;
    #pragma unroll 1
    for (int tap = 0; tap < 81; ++tap)
        wt[(((size_t)tap * (CIN / 16) + kg) * COUT + o) * 16 + cl] = (__bf16)src[tap];
}

// ---------------- fused conv4d (implicit GEMM, 32x32x16 bf16 MFMA) -----------------
// Block 256 thr = 4 waves (2m x 2n). Block tile M=128 (v-span 4), N=2*NT*32.
// Staging unit = one (kt,ku) stage x 32 channels: LDS [row6][chunk4][wp34] x 16B
// = 13056 B; ping-pong 26112 B. Halo slots zero-filled once, DMA exec-masked.
template <int CIN, int COUT, int NT, int WPEU, bool RELU>
__global__ __launch_bounds__(256, WPEU) void conv4d_mfma(
    const __bf16* __restrict__ in_t,   // chunk-planar activations
    const __bf16* __restrict__ wt,     // [81][CIN/16][COUT][16]
    const float* __restrict__ bias,    // [COUT]
    __bf16* __restrict__ out_bf,       // chunk-planar (RELU path)
    float* __restrict__ out_f)         // [2][COUT][65536]  (else)
{
    constexpr int KST   = CIN / 16;
    constexpr int UNITS = CIN / 32;
    constexpr int LOGU  = (UNITS == 2) ? 1 : 2;
    __shared__ __bf16 tile[2 * 6528]; // 2 x 13056 B ping-pong

    const int tid  = threadIdx.x;
    const int lane = tid & 63;
    const int l31  = lane & 31;
    const int hl   = lane >> 5;
    const int wv   = tid >> 6;
    const int gmi  = wv >> 1;          // m wave-row 0..1
    const int gni  = wv & 1;           // n wave-col 0..1

    // grid: xcd(3b) | ulo(1b) | vg(3b) | t(2b) | nb(1b); u = xcd*2+ulo -> 1024
    const int bid = blockIdx.x;
    const int xcd = bid & 7;
    const int s0  = bid >> 3;
    const int u   = xcd * 2 + (s0 & 1);
    const int vg  = (s0 >> 1) & 7;
    const int t   = (s0 >> 4) & 3;
    const int nb  = (s0 >> 6) & 1;
    const int v0  = vg * 4;
    const int pbase = ((t * 16 + u) * 32 + v0) * 32;

    const __bf16* inb = in_t + (size_t)nb * 65536 * CIN;

    // ---- per-lane staging offsets (slot = r*256 + tid), chunk-planar global ----
    int goff[4];
    #pragma unroll
    for (int r = 0; r < 4; ++r) {
        const int slot = r * 256 + tid;            // 16B-chunk slot
        const int row  = slot / 136;               // LDS [row6][chunk4][wp34]
        const int rem  = slot - row * 136;
        const int chunk = rem / 34;
        const int wp   = rem - chunk * 34;
        const int v_in = v0 - 1 + row;
        const int w_in = wp - 1;
        const bool ok = (row < 6) && ((unsigned)v_in < 32u) && ((unsigned)w_in < 32u);
        goff[r] = ok ? (v_in * (CIN * 32) + chunk * 256 + w_in * 8) : -1;
    }

    // ---- one-time zero pre-fill of halo slots (both buffers) ----
    #pragma unroll
    for (int r = 0; r < 4; ++r) {
        const int slot = r * 256 + tid;
        if (slot < 816 && goff[r] < 0) {
            *(uint4*)((char*)tile + slot * 16) = make_uint4(0u, 0u, 0u, 0u);
            *(uint4*)((char*)tile + 13056 + slot * 16) = make_uint4(0u, 0u, 0u, 0u);
        }
    }

    // A-read lane base (16B units): idx = (gmi*2 + rr + kv)*136 + (2ks+hl)*34 + l31+kw
    const int lane_base = gmi * 2 * 136 + hl * 34 + l31;
    const bf16x8* tile16 = (const bf16x8*)tile;

    // B lane pointers: o = (gni*NT+nt)*32 + l31; + hl*8 within the 16-ch group
    const __bf16* wlane[NT];
    #pragma unroll
    for (int nt = 0; nt < NT; ++nt)
        wlane[nt] = wt + ((gni * NT + nt) * 32 + l31) * 16 + hl * 8;

    // ---- valid stage list (block-uniform) ----
    int sb[9], tb0[9], nst = 0;
    #pragma unroll
    for (int kt = 0; kt < 3; ++kt) {
        const int t_in = t + kt - 1;
        if ((unsigned)t_in >= 4u) continue;
        #pragma unroll
        for (int ku = 0; ku < 3; ++ku) {
            const int u_in = u + ku - 1;
            if ((unsigned)u_in >= 16u) continue;
            sb[nst]  = (t_in * 16 + u_in) * 1024 * CIN;   // plane elem offset
            tb0[nst] = (kt * 3 + ku) * 9;
            ++nst;
        }
    }
    const int U = nst * UNITS;

    f32x16 acc[2][NT];
    #pragma unroll
    for (int mt = 0; mt < 2; ++mt)
        #pragma unroll
        for (int nt = 0; nt < NT; ++nt)
            #pragma unroll
            for (int i = 0; i < 16; ++i)
                acc[mt][nt][i] = 0.f;

    // DMA issue for unit j: 4 rounds, exec-masked (halo slots never written)
    auto issue = [&](int j) {
        const int st = j >> LOGU, ch = j & (UNITS - 1);
        const __bf16* gb = inb + sb[st] + ch * 1024;   // unit = 4 chunk-planes
        char* lb = ((char*)tile) + (j & 1) * 13056 + wv * 1024;
        #pragma unroll
        for (int r = 0; r < 4; ++r)
            if (goff[r] >= 0)
                gload_lds16(gb + goff[r], lb + r * 4096);
    };

    issue(0);
    #pragma unroll 1
    for (int i = 0; i < U; ++i) {
        // Force the drain: DMA(i) (issued a full unit ago) + prefill ds_writes.
        asm volatile("s_waitcnt vmcnt(0) lgkmcnt(0)" ::: "memory");
        __syncthreads();
        if (i + 1 < U) issue(i + 1);

        const int st = i >> LOGU, ch = i & (UNITS - 1);
        const int tapb = tb0[st];
        const bf16x8* tb = tile16 + (i & 1) * 816 + lane_base;
        #pragma unroll
        for (int ks = 0; ks < 2; ++ks) {
            const int ksg = ch * 2 + ks;
            #pragma unroll
            for (int kw = 0; kw < 3; ++kw) {
                bf16x8 af[4];
                #pragma unroll
                for (int r = 0; r < 4; ++r)
                    af[r] = tb[r * 136 + ks * 68 + kw];
                bf16x8 bv[3][NT];
                #pragma unroll
                for (int kv = 0; kv < 3; ++kv) {
                    const size_t wo =
                        ((size_t)(tapb + kv * 3 + kw) * KST + ksg) * (COUT * 16);
                    #pragma unroll
                    for (int nt = 0; nt < NT; ++nt)
                        bv[kv][nt] = *(const bf16x8*)(wlane[nt] + wo);
                }
                #pragma unroll
                for (int kv = 0; kv < 3; ++kv)
                    #pragma unroll
                    for (int rr = 0; rr < 2; ++rr)
                        #pragma unroll
                        for (int nt = 0; nt < NT; ++nt)
                            acc[rr][nt] = __builtin_amdgcn_mfma_f32_32x32x16_bf16(
                                af[rr + kv], bv[kv][nt], acc[rr][nt], 0, 0, 0);
            }
        }
    }

    // ---- epilogue: C/D 32x32: col = lane&31, row = (reg&3) + 8*(reg>>2) + 4*hl ----
    #pragma unroll
    for (int nt = 0; nt < NT; ++nt) {
        const int o = (gni * NT + nt) * 32 + l31;
        const float bvls = bias[o];
        #pragma unroll
        for (int mt = 0; mt < 2; ++mt) {
            const int pb = pbase + (gmi * 2 + mt) * 32;
            if constexpr (RELU) {
                #pragma unroll
                for (int rg = 0; rg < 4; ++rg)
                    #pragma unroll
                    for (int j = 0; j < 4; ++j) {
                        float v = acc[mt][nt][rg * 4 + j] + bvls;
                        v = v > 0.f ? v : 0.f;
                        const int p = pb + j + 8 * rg + 4 * hl;
                        const int vv = (p >> 5) & 31, ww = p & 31, tu = p >> 10;
                        out_bf[(size_t)nb * 65536 * COUT +
                               (size_t)(tu * 32 + vv) * (32 * COUT) +
                               (o >> 3) * 256 + ww * 8 + (o & 7)] = (__bf16)v;
                    }
            } else {
                #pragma unroll
                for (int rg = 0; rg < 4; ++rg) {
                    f32x4 sv;
                    #pragma unroll
                    for (int j = 0; j < 4; ++j)
                        sv[j] = acc[mt][nt][rg * 4 + j] + bvls;
                    const int p = pb + 8 * rg + 4 * hl;
                    *(f32x4*)(out_f + ((size_t)nb * COUT + o) * 65536 + p) = sv;
                }
            }
        }
    }
}

extern "C" void kernel_launch(void* const* d_in, const int* in_sizes, int n_in,
                              void* d_out, int out_size, void* d_ws, size_t ws_size,
                              hipStream_t stream) {
    const float* x  = (const float*)d_in[0];
    const float* w1 = (const float*)d_in[1];
    const float* b1 = (const float*)d_in[2];
    const float* w2 = (const float*)d_in[3];
    const float* b2 = (const float*)d_in[4];
    float* out = (float*)d_out;

    char* ws = (char*)d_ws;
    __bf16* x_t = (__bf16*)ws;                               // 16,777,216 B
    __bf16* h_t = (__bf16*)(ws + 16777216);                  // 33,554,432 B
    __bf16* w1t = (__bf16*)(ws + 50331648);                  //  1,327,104 B
    __bf16* w2t = (__bf16*)(ws + 51658752);                  //  1,327,104 B

    cvt_x<<<dim3(1024, 2), 256, 0, stream>>>(x, x_t);
    cvt_w<64><<<32, 256, 0, stream>>>(w1, w1t);
    cvt_w<128><<<32, 256, 0, stream>>>(w2, w2t);

    // conv1: wave 64x64 (NT=2), 2 units/stage, 3 blocks/CU, relu -> chunk-planar
    conv4d_mfma<64, 128, 2, 3, true><<<1024, 256, 0, stream>>>(x_t, w1t, b1, h_t,
                                                               nullptr);
    // conv2: wave 64x32 (NT=1), 4 units/stage, 4 blocks/CU, fp32 planar out
    conv4d_mfma<128, 64, 1, 4, false><<<1024, 256, 0, stream>>>(h_t, w2t, b2, nullptr,
                                                                out);
}